// Round 14
// baseline (2130.187 us; speedup 1.0000x reference)
//
#include <hip/hip_runtime.h>
#include <stdint.h>

#define TSTEPS 512
#define BATCH  4096
// R14: occupancy push. 1024 blocks x 512 threads, 4 batch rows/block
// (valid rows at MFMA m = 4*r; acc reg 0 of quad lq owns batch row lq).
// VGPR has been 64 since R8 -> 8 waves/SIMD fit; grid was the limiter
// (512 blocks = 16 waves/CU). Now 4 blocks/CU = 32 waves/CU: barrier
// convoys + MFMA/trans latency hidden by 4 independent blocks.
// Loop body = R10's proven runtime-parity structure; scalar EW (1 row/lane);
// cheap +0x8000>>16 bf16 pack (absmax-neutral since R12).
// MFMA work doubles (75% padded rows) but ~350-580 cyc/SIMD-step stays
// below the ~950-cyc VALU budget.

typedef __attribute__((ext_vector_type(8))) short bf16x8;
typedef __attribute__((ext_vector_type(4))) float f32x4;
typedef __attribute__((ext_vector_type(2))) float f32x2;

#define SRZ (-1.4426950408889634f)   /* -log2(e): r,z gates */
#define SN  ( 2.8853900817779268f)   /* 2*log2(e): n gate   */

__device__ __forceinline__ short f2bf(float f) {   // setup only
    uint32_t u = __float_as_uint(f);
    uint32_t r = (u + 0x7fffu + ((u >> 16) & 1u)) >> 16;
    return (short)r;
}
__device__ __forceinline__ float fast_rcp(float x) { return __builtin_amdgcn_rcpf(x); }
#if __has_builtin(__builtin_amdgcn_exp2f)
__device__ __forceinline__ float exp2_fast(float x) { return __builtin_amdgcn_exp2f(x); }
#else
__device__ __forceinline__ float exp2_fast(float x) { return __expf(x * 0.6931471805599453f); }
#endif
// pre-scaled sigmoid / tanh (scalar, one batch row per lane)
__device__ __forceinline__ float sigp(float y) { return fast_rcp(1.0f + exp2_fast(y)); }
__device__ __forceinline__ float tanhp(float y) { return fmaf(-2.0f, sigp(y), 1.0f); }

__global__ __launch_bounds__(512, 8) void gru_fused(
    const float* __restrict__ x,     // [T,B,2]
    const float* __restrict__ Wih0,  // [192,2]
    const float* __restrict__ Whh0,  // [192,64]
    const float* __restrict__ bih0,  // [192]
    const float* __restrict__ bhh0,  // [192]
    const float* __restrict__ Wih1,  // [192,64]
    const float* __restrict__ Whh1,  // [192,64]
    const float* __restrict__ bih1,  // [192]
    const float* __restrict__ bhh1,  // [192]
    const float* __restrict__ Wp,    // [128]
    const float* __restrict__ bp,    // [1]
    float* __restrict__ out)         // [B]
{
    const int tid  = threadIdx.x;
    const int wv   = tid >> 6;      // wave 0..7
    const int isL0 = (wv < 4);
    const int w4   = wv & 3;
    const int l    = tid & 63;
    const int lm   = l & 15;        // A row m / n-col within tile
    const int lq   = l >> 4;        // quad; batch row this lane owns
    const int b0   = blockIdx.x * 4;
    const int j    = w4 * 16 + lm;  // hidden index this lane owns

    // Batch row r (0..3) at MFMA row m = 4*r; rows m&3!=0 stay zero forever.
    __shared__ short h0A[2][16 * 72];
    __shared__ short h1A[2][16 * 72];
    __shared__ float Pf[4][64];

    for (int idx = tid; idx < 2 * 16 * 72; idx += 512) {
        ((short*)h0A)[idx] = 0;
        ((short*)h1A)[idx] = 0;
    }
    __syncthreads();

    const int aoff = lm * 72 + lq * 8;        // A-frag read (shorts); +32 K-half 1
    const int so   = (lq * 4) * 72 + j;       // store offset: row m=4*lq, col j

    if (isL0) {
        // ================= layer-0 waves =================
        bf16x8 w0[3][2];   // Whh0, gate-prescaled, single bf16
#pragma unroll
        for (int g = 0; g < 3; ++g) {
            const int row = g * 64 + j;
            const float sc = (g == 2) ? SN : SRZ;
#pragma unroll
            for (int q = 0; q < 2; ++q) {
                const float* p = Whh0 + row * 64 + q * 32 + lq * 8;
                bf16x8 vh;
#pragma unroll
                for (int i = 0; i < 8; ++i) vh[i] = f2bf(p[i] * sc);
                w0[g][q] = vh;
            }
        }
        const float wr0 = SRZ * Wih0[j * 2 + 0],         wr1 = SRZ * Wih0[j * 2 + 1];
        const float wz0 = SRZ * Wih0[(64 + j) * 2 + 0],  wz1 = SRZ * Wih0[(64 + j) * 2 + 1];
        const float wn0 = SN  * Wih0[(128 + j) * 2 + 0], wn1 = SN  * Wih0[(128 + j) * 2 + 1];
        const float cb[3] = { SRZ * (bih0[j] + bhh0[j]),
                              SRZ * (bih0[64 + j] + bhh0[64 + j]),
                              SN  * bhh0[128 + j] };
        const float bn = SN * bih0[128 + j];

        float h0r = 0.f;
        const float* xp = x + (size_t)(b0 + lq) * 2;
        f32x2 xc = *(const f32x2*)xp;
        f32x2 xnb = xc;

        for (int t = 0; t <= TSTEPS; ++t) {
            const int pr = t & 1, pw = pr ^ 1;
            bf16x8 a00 = *(const bf16x8*)&h0A[pr][aoff];
            bf16x8 a01 = *(const bf16x8*)&h0A[pr][aoff + 32];

            if (t + 1 < TSTEPS) {
                xp += (size_t)BATCH * 2;
                xnb = *(const f32x2*)xp;
            }

            f32x4 hg0[3];
#pragma unroll
            for (int g = 0; g < 3; ++g) {
                const f32x4 ci = {cb[g], cb[g], cb[g], cb[g]};
                f32x4 c;
                c = __builtin_amdgcn_mfma_f32_16x16x32_bf16(a00, w0[g][0], ci, 0, 0, 0);
                hg0[g] = __builtin_amdgcn_mfma_f32_16x16x32_bf16(a01, w0[g][1], c, 0, 0, 0);
            }

            if (t < TSTEPS) {
                const float x0 = xc[0], x1 = xc[1];
                const float r = sigp(fmaf(wr0, x0, fmaf(wr1, x1, hg0[0][0])));
                const float z = sigp(fmaf(wz0, x0, fmaf(wz1, x1, hg0[1][0])));
                const float n = tanhp(fmaf(r, hg0[2][0], fmaf(wn0, x0, fmaf(wn1, x1, bn))));
                const float h = fmaf(z, h0r - n, n);
                h0r = h;
                h0A[pw][so] = (short)((__float_as_uint(h) + 0x8000u) >> 16);
            }
            xc = xnb;
            __syncthreads();   // barrier 1..513
        }

        Pf[lq][j] = Wp[j] * h0r;
        __syncthreads();       // barrier 514
        __syncthreads();       // barrier 515
    } else {
        // ================= layer-1 waves =================
        bf16x8 w1[3][2], w2[3][2];
#pragma unroll
        for (int g = 0; g < 3; ++g) {
            const int row = g * 64 + j;
            const float sc = (g == 2) ? SN : SRZ;
#pragma unroll
            for (int q = 0; q < 2; ++q) {
                const float* p1 = Wih1 + row * 64 + q * 32 + lq * 8;
                const float* p2 = Whh1 + row * 64 + q * 32 + lq * 8;
                bf16x8 v1, v2;
#pragma unroll
                for (int i = 0; i < 8; ++i) {
                    v1[i] = f2bf(p1[i] * sc);
                    v2[i] = f2bf(p2[i] * sc);
                }
                w1[g][q] = v1; w2[g][q] = v2;
            }
        }
        const float cb[3] = { SRZ * (bih1[j] + bhh1[j]),
                              SRZ * (bih1[64 + j] + bhh1[64 + j]),
                              SN  * bih1[128 + j] };
        const float ce2 = SN * bhh1[128 + j];

        float h1r = 0.f;

        for (int t = 0; t <= TSTEPS; ++t) {
            const int pr = t & 1, pw = pr ^ 1;
            bf16x8 a00 = *(const bf16x8*)&h0A[pr][aoff];
            bf16x8 a01 = *(const bf16x8*)&h0A[pr][aoff + 32];
            bf16x8 a10 = *(const bf16x8*)&h1A[pr][aoff];
            bf16x8 a11 = *(const bf16x8*)&h1A[pr][aoff + 32];

            f32x4 xg1[3], hg1[3];
#pragma unroll
            for (int g = 0; g < 3; ++g) {
                const f32x4 ci = {cb[g], cb[g], cb[g], cb[g]};
                const float ev = (g == 2) ? ce2 : 0.0f;
                const f32x4 ei = {ev, ev, ev, ev};
                f32x4 d;
                d = __builtin_amdgcn_mfma_f32_16x16x32_bf16(a00, w1[g][0], ci, 0, 0, 0);
                xg1[g] = __builtin_amdgcn_mfma_f32_16x16x32_bf16(a01, w1[g][1], d, 0, 0, 0);
                f32x4 e;
                e = __builtin_amdgcn_mfma_f32_16x16x32_bf16(a10, w2[g][0], ei, 0, 0, 0);
                hg1[g] = __builtin_amdgcn_mfma_f32_16x16x32_bf16(a11, w2[g][1], e, 0, 0, 0);
            }

            if (t > 0) {
                const float r = sigp(xg1[0][0] + hg1[0][0]);
                const float z = sigp(xg1[1][0] + hg1[1][0]);
                const float n = tanhp(fmaf(r, hg1[2][0], xg1[2][0]));
                const float h = fmaf(z, h1r - n, n);
                h1r = h;
                h1A[pw][so] = (short)((__float_as_uint(h) + 0x8000u) >> 16);
            }
            __syncthreads();   // barrier 1..513
        }

        __syncthreads();       // barrier 514 (Pf written by L0 waves)
        Pf[lq][j] += Wp[64 + j] * h1r;
        __syncthreads();       // barrier 515
    }

    // ---- final reduce: out[b] = sum_j Pf[row][j] + bp ----
    if (tid < 4) {
        float s = bp[0];
#pragma unroll 8
        for (int k = 0; k < 64; ++k) s += Pf[tid][k];
        out[b0 + tid] = s;
    }
}

extern "C" void kernel_launch(void* const* d_in, const int* in_sizes, int n_in,
                              void* d_out, int out_size, void* d_ws, size_t ws_size,
                              hipStream_t stream) {
    (void)in_sizes; (void)n_in; (void)out_size; (void)d_ws; (void)ws_size;
    gru_fused<<<dim3(BATCH / 4), dim3(512), 0, stream>>>(
        (const float*)d_in[0], (const float*)d_in[1], (const float*)d_in[2],
        (const float*)d_in[3], (const float*)d_in[4], (const float*)d_in[5],
        (const float*)d_in[6], (const float*)d_in[7], (const float*)d_in[8],
        (const float*)d_in[9], (const float*)d_in[10], (float*)d_out);
}

// Round 15
// 391.414 us; speedup vs baseline: 5.4423x; 5.4423x over previous
//
#include <hip/hip_runtime.h>
#include <stdint.h>

#define TSTEPS 512
#define BATCH  4096
// R15 = exact R10 revert (empirical best: 392 us headline / 363 steady).
// 512 blocks x 512 thr, 8 rows/block, wave-specialized (waves 0-3: hg0+EW0,
// waves 4-7: xg1+hg1+EW1), single-bf16 prescaled weights in registers,
// packed-f32x2 EW, global x prefetch, 1 barrier/step, plain b16 stores.
// Register ladder (measured): (512,2)->no spill/2 blocks; (512,4)->fits,
// best; (512,8)->64-cap, 6 GB spill (R14). TLP ceiling = 2 blocks/CU.
// Failed variants: R9 swizzle-store (+LDS pipe), R11 x-in-LDS (+EW latency),
// R12 merged 4-deep MFMA chains (+dep latency), R13 shared-rcp (neutral-),
// R14 occupancy push (spill).

typedef __attribute__((ext_vector_type(8))) short bf16x8;
typedef __attribute__((ext_vector_type(4))) float f32x4;
typedef __attribute__((ext_vector_type(2))) float f32x2;

#define SRZ (-1.4426950408889634f)   /* -log2(e): r,z gates */
#define SN  ( 2.8853900817779268f)   /* 2*log2(e): n gate   */

__device__ __forceinline__ short f2bf(float f) {
    uint32_t u = __float_as_uint(f);
    uint32_t r = (u + 0x7fffu + ((u >> 16) & 1u)) >> 16;
    return (short)r;
}
__device__ __forceinline__ float fast_rcp(float x) { return __builtin_amdgcn_rcpf(x); }
#if __has_builtin(__builtin_amdgcn_exp2f)
__device__ __forceinline__ float exp2_fast(float x) { return __builtin_amdgcn_exp2f(x); }
#else
__device__ __forceinline__ float exp2_fast(float x) { return __expf(x * 0.6931471805599453f); }
#endif

__device__ __forceinline__ f32x2 fma2(f32x2 a, f32x2 b, f32x2 c) {
    return __builtin_elementwise_fma(a, b, c);
}
__device__ __forceinline__ f32x2 splat2(float s) { return (f32x2){s, s}; }
// sigmoid of pre-scaled arg: rcp(1 + exp2(y)), over 2 rows
__device__ __forceinline__ f32x2 sig2(f32x2 y) {
    f32x2 a = {exp2_fast(y[0]), exp2_fast(y[1])};
    a = a + splat2(1.0f);                     // v_pk_add_f32
    return (f32x2){fast_rcp(a[0]), fast_rcp(a[1])};
}
// tanh of pre-scaled arg: 1 - 2*sig2(y)
__device__ __forceinline__ f32x2 tanh2(f32x2 y) {
    return fma2(splat2(-2.0f), sig2(y), splat2(1.0f));
}

__global__ __launch_bounds__(512, 4) void gru_fused(
    const float* __restrict__ x,     // [T,B,2]
    const float* __restrict__ Wih0,  // [192,2]
    const float* __restrict__ Whh0,  // [192,64]
    const float* __restrict__ bih0,  // [192]
    const float* __restrict__ bhh0,  // [192]
    const float* __restrict__ Wih1,  // [192,64]
    const float* __restrict__ Whh1,  // [192,64]
    const float* __restrict__ bih1,  // [192]
    const float* __restrict__ bhh1,  // [192]
    const float* __restrict__ Wp,    // [128]
    const float* __restrict__ bp,    // [1]
    float* __restrict__ out)         // [B]
{
    const int tid  = threadIdx.x;
    const int wv   = tid >> 6;      // wave 0..7
    const int isL0 = (wv < 4);
    const int w4   = wv & 3;
    const int l    = tid & 63;
    const int lm   = l & 15;        // A row m / n-col within tile
    const int lq   = l >> 4;        // quad
    const int b0   = blockIdx.x * 8;
    const int j    = w4 * 16 + lm;  // hidden index this lane owns

    // Batch row r (0..7) at MFMA row m = lq*4 + i (r = lq*2+i, i in {0,1});
    // rows with m&3 >= 2 stay zero forever.
    __shared__ short h0A[2][16 * 72];
    __shared__ short h1A[2][16 * 72];
    __shared__ float Pf[8][64];

    for (int idx = tid; idx < 2 * 16 * 72; idx += 512) {
        ((short*)h0A)[idx] = 0;
        ((short*)h1A)[idx] = 0;
    }
    __syncthreads();

    const int aoff = lm * 72 + lq * 8;  // shorts; +32 for K-half 1

    if (isL0) {
        // ================= layer-0 waves =================
        bf16x8 w0[3][2];   // Whh0, gate-prescaled, single bf16
#pragma unroll
        for (int g = 0; g < 3; ++g) {
            const int row = g * 64 + j;
            const float sc = (g == 2) ? SN : SRZ;
#pragma unroll
            for (int q = 0; q < 2; ++q) {
                const float* p = Whh0 + row * 64 + q * 32 + lq * 8;
                bf16x8 vh;
#pragma unroll
                for (int i = 0; i < 8; ++i) vh[i] = f2bf(p[i] * sc);
                w0[g][q] = vh;
            }
        }
        const f32x2 wr0 = splat2(SRZ * Wih0[j * 2 + 0]), wr1 = splat2(SRZ * Wih0[j * 2 + 1]);
        const f32x2 wz0 = splat2(SRZ * Wih0[(64 + j) * 2 + 0]), wz1 = splat2(SRZ * Wih0[(64 + j) * 2 + 1]);
        const f32x2 wn0 = splat2(SN * Wih0[(128 + j) * 2 + 0]), wn1 = splat2(SN * Wih0[(128 + j) * 2 + 1]);
        const float cb[3] = { SRZ * (bih0[j] + bhh0[j]),
                              SRZ * (bih0[64 + j] + bhh0[64 + j]),
                              SN  * bhh0[128 + j] };
        const f32x2 bn = splat2(SN * bih0[128 + j]);

        f32x2 h0rv = {0.f, 0.f};
        const float* xp = x + (size_t)(b0 + lq * 2) * 2;
        f32x4 xc = *(const f32x4*)xp;
        f32x4 xnb = xc;

        for (int t = 0; t <= TSTEPS; ++t) {
            const int pr = t & 1, pw = pr ^ 1;
            bf16x8 a00 = *(const bf16x8*)&h0A[pr][aoff];
            bf16x8 a01 = *(const bf16x8*)&h0A[pr][aoff + 32];

            if (t + 1 < TSTEPS) {
                xp += (size_t)BATCH * 2;
                xnb = *(const f32x4*)xp;
            }

            f32x4 hg0[3];
#pragma unroll
            for (int g = 0; g < 3; ++g) {
                const f32x4 ci = {cb[g], cb[g], cb[g], cb[g]};
                f32x4 c;
                c = __builtin_amdgcn_mfma_f32_16x16x32_bf16(a00, w0[g][0], ci, 0, 0, 0);
                hg0[g] = __builtin_amdgcn_mfma_f32_16x16x32_bf16(a01, w0[g][1], c, 0, 0, 0);
            }

            if (t < TSTEPS) {
                // acc regs 0,1 = the two valid rows (adjacent VGPRs -> free f32x2)
                const f32x2 x0v = {xc[0], xc[2]}, x1v = {xc[1], xc[3]};
                const f32x2 hgr = {hg0[0][0], hg0[0][1]};
                const f32x2 hgz = {hg0[1][0], hg0[1][1]};
                const f32x2 hgn = {hg0[2][0], hg0[2][1]};
                const f32x2 rv = sig2(fma2(wr0, x0v, fma2(wr1, x1v, hgr)));
                const f32x2 zv = sig2(fma2(wz0, x0v, fma2(wz1, x1v, hgz)));
                const f32x2 nv = tanh2(fma2(rv, hgn, fma2(wn0, x0v, fma2(wn1, x1v, bn))));
                const f32x2 hv = fma2(zv, h0rv - nv, nv);
                h0rv = hv;
                h0A[pw][(lq * 4 + 0) * 72 + j] = f2bf(hv[0]);
                h0A[pw][(lq * 4 + 1) * 72 + j] = f2bf(hv[1]);
            }
            xc = xnb;
            __syncthreads();   // barrier 1..513
        }

        const float wp0 = Wp[j];
        Pf[lq * 2 + 0][j] = wp0 * h0rv[0];
        Pf[lq * 2 + 1][j] = wp0 * h0rv[1];
        __syncthreads();       // barrier 514
        __syncthreads();       // barrier 515
    } else {
        // ================= layer-1 waves =================
        bf16x8 w1[3][2], w2[3][2];   // Wih1, Whh1, gate-prescaled, single bf16
#pragma unroll
        for (int g = 0; g < 3; ++g) {
            const int row = g * 64 + j;
            const float sc = (g == 2) ? SN : SRZ;
#pragma unroll
            for (int q = 0; q < 2; ++q) {
                const float* p1 = Wih1 + row * 64 + q * 32 + lq * 8;
                const float* p2 = Whh1 + row * 64 + q * 32 + lq * 8;
                bf16x8 v1, v2;
#pragma unroll
                for (int i = 0; i < 8; ++i) {
                    v1[i] = f2bf(p1[i] * sc);
                    v2[i] = f2bf(p2[i] * sc);
                }
                w1[g][q] = v1; w2[g][q] = v2;
            }
        }
        const float cb[3] = { SRZ * (bih1[j] + bhh1[j]),
                              SRZ * (bih1[64 + j] + bhh1[64 + j]),
                              SN  * bih1[128 + j] };
        // bh1_n folded into hg1's C-init (it is multiplied by r later:
        // n = tanh(r*(Whh1n.h + bhh1n) + Wih1n.h0 + bih1n))
        const float ce2 = SN * bhh1[128 + j];

        f32x2 h1rv = {0.f, 0.f};

        for (int t = 0; t <= TSTEPS; ++t) {
            const int pr = t & 1, pw = pr ^ 1;
            bf16x8 a00 = *(const bf16x8*)&h0A[pr][aoff];
            bf16x8 a01 = *(const bf16x8*)&h0A[pr][aoff + 32];
            bf16x8 a10 = *(const bf16x8*)&h1A[pr][aoff];
            bf16x8 a11 = *(const bf16x8*)&h1A[pr][aoff + 32];

            f32x4 xg1[3], hg1[3];
#pragma unroll
            for (int g = 0; g < 3; ++g) {
                const f32x4 ci = {cb[g], cb[g], cb[g], cb[g]};
                const float ev = (g == 2) ? ce2 : 0.0f;
                const f32x4 ei = {ev, ev, ev, ev};
                f32x4 d;
                d = __builtin_amdgcn_mfma_f32_16x16x32_bf16(a00, w1[g][0], ci, 0, 0, 0);
                xg1[g] = __builtin_amdgcn_mfma_f32_16x16x32_bf16(a01, w1[g][1], d, 0, 0, 0);
                f32x4 e;
                e = __builtin_amdgcn_mfma_f32_16x16x32_bf16(a10, w2[g][0], ei, 0, 0, 0);
                hg1[g] = __builtin_amdgcn_mfma_f32_16x16x32_bf16(a11, w2[g][1], e, 0, 0, 0);
            }

            if (t > 0) {
                const f32x2 xgr = {xg1[0][0], xg1[0][1]}, hgr = {hg1[0][0], hg1[0][1]};
                const f32x2 xgz = {xg1[1][0], xg1[1][1]}, hgz = {hg1[1][0], hg1[1][1]};
                const f32x2 xgn = {xg1[2][0], xg1[2][1]}, hgn = {hg1[2][0], hg1[2][1]};
                const f32x2 rv = sig2(xgr + hgr);
                const f32x2 zv = sig2(xgz + hgz);
                const f32x2 nv = tanh2(fma2(rv, hgn, xgn));
                const f32x2 hv = fma2(zv, h1rv - nv, nv);
                h1rv = hv;
                h1A[pw][(lq * 4 + 0) * 72 + j] = f2bf(hv[0]);
                h1A[pw][(lq * 4 + 1) * 72 + j] = f2bf(hv[1]);
            }
            __syncthreads();   // barrier 1..513
        }

        __syncthreads();       // barrier 514 (Pf written by L0 waves)
        const float wp1 = Wp[64 + j];
        Pf[lq * 2 + 0][j] += wp1 * h1rv[0];
        Pf[lq * 2 + 1][j] += wp1 * h1rv[1];
        __syncthreads();       // barrier 515
    }

    // ---- final reduce: out[b] = sum_j Pf[row][j] + bp ----
    if (tid < 8) {
        float s = bp[0];
#pragma unroll 8
        for (int k = 0; k < 64; ++k) s += Pf[tid][k];
        out[b0 + tid] = s;
    }
}

extern "C" void kernel_launch(void* const* d_in, const int* in_sizes, int n_in,
                              void* d_out, int out_size, void* d_ws, size_t ws_size,
                              hipStream_t stream) {
    (void)in_sizes; (void)n_in; (void)out_size; (void)d_ws; (void)ws_size;
    gru_fused<<<dim3(BATCH / 8), dim3(512), 0, stream>>>(
        (const float*)d_in[0], (const float*)d_in[1], (const float*)d_in[2],
        (const float*)d_in[3], (const float*)d_in[4], (const float*)d_in[5],
        (const float*)d_in[6], (const float*)d_in[7], (const float*)d_in[8],
        (const float*)d_in[9], (const float*)d_in[10], (float*)d_out);
}